// Round 12
// baseline (7299.017 us; speedup 1.0000x reference)
//
#include <hip/hip_runtime.h>

// ---------------- problem dims ----------------
#define S_LEN 128
#define BATCH 64
#define EDIM  512
#define PLEN  160
#define PDIM  512
#define HDIM  1024
#define G3    3072      // 3*H
#define PROWS 144       // post rows staged in LDS per attn block; rest streamed

typedef _Float16 half8v  __attribute__((ext_vector_type(8)));
typedef _Float16 half4v  __attribute__((ext_vector_type(4)));
typedef _Float16 half2v  __attribute__((ext_vector_type(2)));
typedef float    f32x4   __attribute__((ext_vector_type(4)));

// ---------------- workspace layout (bytes) ----------------
#define OFF_WIH  ((size_t)0)                                  // fp16 [3072][1024]
#define OFF_WHH  (OFF_WIH  + (size_t)G3*HDIM*2)               // fp16 [3072][1024]
#define OFF_WQH  (OFF_WHH  + (size_t)G3*HDIM*2)               // fp16 [512][1024]
#define OFF_INC  (OFF_WQH  + (size_t)PDIM*HDIM*2)             // fp16 [128][64][512]
#define OFF_POST (OFF_INC  + (size_t)S_LEN*BATCH*EDIM*2)      // fp16 [160][64][512]
#define OFF_HB   (OFF_POST + (size_t)PLEN*BATCH*PDIM*2)       // fp16 [2][64][1024]
#define OFF_QH   (OFF_HB   + (size_t)2*BATCH*HDIM*2)          // fp16 [64][512]
#define OFF_CTX  (OFF_QH   + (size_t)BATCH*PDIM*2)            // fp16 [64][512]
// total ~31.5 MB — no ctrl/flags: kernel boundaries are the sync

__device__ __forceinline__ float wave_sum(float v) {
    v += __shfl_xor(v, 32); v += __shfl_xor(v, 16); v += __shfl_xor(v, 8);
    v += __shfl_xor(v, 4);  v += __shfl_xor(v, 2);  v += __shfl_xor(v, 1);
    return v;
}
__device__ __forceinline__ float wave_max(float v) {
    v = fmaxf(v, __shfl_xor(v, 32)); v = fmaxf(v, __shfl_xor(v, 16));
    v = fmaxf(v, __shfl_xor(v, 8));  v = fmaxf(v, __shfl_xor(v, 4));
    v = fmaxf(v, __shfl_xor(v, 2));  v = fmaxf(v, __shfl_xor(v, 1));
    return v;
}

// one 16x16 output tile accumulation: D[m,n] += sum_k A[m,k] * W[n,k]
__device__ __forceinline__ void mfma_acc(f32x4& acc, const _Float16* __restrict__ A, int lda,
                                         const _Float16* __restrict__ Bb, int ldb,
                                         int ksteps, int lane) {
    const _Float16* ap = A  + (size_t)(lane & 15) * lda + ((lane >> 4) << 3);
    const _Float16* bp = Bb + (size_t)(lane & 15) * ldb + ((lane >> 4) << 3);
    #pragma unroll
    for (int ks = 0; ks < ksteps; ++ks) {
        half8v av = *(const half8v*)ap;
        half8v bv = *(const half8v*)bp;
        acc = __builtin_amdgcn_mfma_f32_16x16x32_f16(av, bv, acc, 0, 0, 0);
        ap += 32; bp += 32;
    }
}

// three output tiles sharing one A stream (r,z,n gate rows)
__device__ __forceinline__ void mfma_acc3(f32x4& a0, f32x4& a1, f32x4& a2,
        const _Float16* __restrict__ A, int lda,
        const _Float16* __restrict__ B0, const _Float16* __restrict__ B1,
        const _Float16* __restrict__ B2, int ldb, int ksteps, int lane) {
    const _Float16* ap = A  + (size_t)(lane & 15) * lda + ((lane >> 4) << 3);
    const _Float16* p0 = B0 + (size_t)(lane & 15) * ldb + ((lane >> 4) << 3);
    const _Float16* p1 = B1 + (size_t)(lane & 15) * ldb + ((lane >> 4) << 3);
    const _Float16* p2 = B2 + (size_t)(lane & 15) * ldb + ((lane >> 4) << 3);
    #pragma unroll
    for (int ks = 0; ks < ksteps; ++ks) {
        half8v av = *(const half8v*)ap;
        a0 = __builtin_amdgcn_mfma_f32_16x16x32_f16(av, *(const half8v*)p0, a0, 0, 0, 0);
        a1 = __builtin_amdgcn_mfma_f32_16x16x32_f16(av, *(const half8v*)p1, a1, 0, 0, 0);
        a2 = __builtin_amdgcn_mfma_f32_16x16x32_f16(av, *(const half8v*)p2, a2, 0, 0, 0);
        ap += 32; p0 += 32; p1 += 32; p2 += 32;
    }
}

// ======== stage kernel (once per replay): fp32 -> fp16 + h0 init ========
__global__ __launch_bounds__(256) void k_stage(
    const float* __restrict__ w_ih, const float* __restrict__ w_hh,
    const float* __restrict__ wq,   const float* __restrict__ incoming,
    const float* __restrict__ post, const float* __restrict__ h_init,
    char* __restrict__ ws)
{
    _Float16* wih_h  = (_Float16*)(ws + OFF_WIH);
    _Float16* whh_h  = (_Float16*)(ws + OFF_WHH);
    _Float16* wq_h   = (_Float16*)(ws + OFF_WQH);
    _Float16* inc_h  = (_Float16*)(ws + OFF_INC);
    _Float16* post_h = (_Float16*)(ws + OFF_POST);
    _Float16* hb     = (_Float16*)(ws + OFF_HB);
    const int NV4_W    = G3*HDIM/4;
    const int NV4_WQ   = PDIM*HDIM/4;
    const int NV4_INC  = S_LEN*BATCH*EDIM/4;
    const int NV4_POST = PLEN*BATCH*PDIM/4;
    const int TOT = 2*NV4_W + NV4_WQ + NV4_INC + NV4_POST;
    const int gs = gridDim.x * blockDim.x;
    for (int i = blockIdx.x*blockDim.x + threadIdx.x; i < TOT; i += gs) {
        const float* s; _Float16* dp; int o;
        if (i < NV4_W)                          { s = w_ih;     dp = wih_h;  o = i; }
        else if (i < 2*NV4_W)                   { s = w_hh;     dp = whh_h;  o = i - NV4_W; }
        else if (i < 2*NV4_W + NV4_WQ)          { s = wq;       dp = wq_h;   o = i - 2*NV4_W; }
        else if (i < 2*NV4_W + NV4_WQ + NV4_INC){ s = incoming; dp = inc_h;  o = i - 2*NV4_W - NV4_WQ; }
        else                                    { s = post;     dp = post_h; o = i - 2*NV4_W - NV4_WQ - NV4_INC; }
        f32x4 v = *(const f32x4*)(s + (size_t)o*4);
        half4v hv4 = {(_Float16)v.x, (_Float16)v.y, (_Float16)v.z, (_Float16)v.w};
        *(half4v*)(dp + (size_t)o*4) = hv4;
    }
    for (int i = blockIdx.x*blockDim.x + threadIdx.x; i < BATCH*HDIM; i += gs)
        hb[i] = (_Float16)h_init[i & (HDIM-1)];   // hb buffer 0 = h(0)
}

// ======== query kernel (per step): 128 blocks x 64 thr, one 16x16 tile ========
__global__ __launch_bounds__(64) void k_query(
    const float* __restrict__ bq, int t, char* __restrict__ ws)
{
    const int lane = threadIdx.x;
    const int mt = blockIdx.x >> 5;        // 4 row tiles (batches)
    const int nt = blockIdx.x & 31;        // 32 col tiles (query dims)
    const _Float16* hb   = (const _Float16*)(ws + OFF_HB) + (size_t)(t & 1)*BATCH*HDIM;
    const _Float16* wq_h = (const _Float16*)(ws + OFF_WQH);
    _Float16* query_h    = (_Float16*)(ws + OFF_QH);
    f32x4 qa = {0.f,0.f,0.f,0.f};
    mfma_acc(qa, hb + (size_t)(mt*16)*HDIM, HDIM,
             wq_h + (size_t)(nt*16)*HDIM, HDIM, HDIM/32, lane);
    const int col = nt*16 + (lane & 15);
    const int r0  = mt*16 + ((lane >> 4) << 2);
    const float b = bq[col];
    #pragma unroll
    for (int r = 0; r < 4; ++r)
        query_h[(size_t)(r0+r)*PDIM + col] = (_Float16)(qa[r] + b);
}

// ======== attention kernel (per step): 64 blocks x 256 thr, one batch each ========
__global__ __launch_bounds__(256) void k_attn(
    const int* __restrict__ post_length, int t, char* __restrict__ ws)
{
    const int tid  = threadIdx.x;
    const int lane = tid & 63;
    const int wv   = tid >> 6;
    const int ab   = blockIdx.x;
    const _Float16* post_h  = (const _Float16*)(ws + OFF_POST);
    const _Float16* query_h = (const _Float16*)(ws + OFF_QH);
    _Float16* ctx_h         = (_Float16*)(ws + OFF_CTX);

    __shared__ __align__(16) _Float16 s_post[PROWS * PDIM];   // 144 KB
    __shared__ __align__(16) _Float16 s_q[PDIM];
    __shared__ float s_scores[PLEN];
    __shared__ float s_w[PLEN];
    __shared__ float s_bc[2];

    const int plen = post_length[ab];
    // stage post rows 0..PROWS-1 (fp16 global -> LDS), 16B vectorized
    for (int i = tid; i < PROWS*PDIM/8; i += 256) {
        const int p = i >> 6, v = i & 63;
        ((half8v*)s_post)[i] = *(const half8v*)(post_h + ((size_t)p*BATCH + ab)*PDIM + v*8);
    }
    // streamed rows 144..159 into registers
    half8v srow[4];
    #pragma unroll
    for (int i = 0; i < 4; ++i)
        srow[i] = *(const half8v*)(post_h + ((size_t)(PROWS + wv + 4*i)*BATCH + ab)*PDIM + lane*8);
    if (tid < PDIM/8)
        *(half8v*)&s_q[tid*8] = *(const half8v*)&query_h[(size_t)ab*PDIM + tid*8];
    __syncthreads();

    // scores = post . query (identical numerics to R11)
    const half8v qv = *(const half8v*)&s_q[lane*8];
    #pragma unroll 2
    for (int p = wv; p < PROWS; p += 4) {
        const half8v pv = *(const half8v*)&s_post[(size_t)p*PDIM + lane*8];
        float sd = 0.f;
        #pragma unroll
        for (int jj = 0; jj < 8; ++jj) sd += (float)pv[jj] * (float)qv[jj];
        sd = wave_sum(sd);
        if (lane == 0) s_scores[p] = sd;
    }
    #pragma unroll
    for (int i = 0; i < 4; ++i) {
        const half8v pv = srow[i];
        float sd = 0.f;
        #pragma unroll
        for (int jj = 0; jj < 8; ++jj) sd += (float)pv[jj] * (float)qv[jj];
        sd = wave_sum(sd);
        if (lane == 0) s_scores[PROWS + wv + 4*i] = sd;
    }
    __syncthreads();
    if (wv == 0) {
        float m = -1e30f;
        for (int p = lane; p < plen; p += 64) m = fmaxf(m, s_scores[p]);
        m = wave_max(m);
        if (lane == 0) s_bc[0] = m;
    }
    __syncthreads();
    const float mx = s_bc[0];
    if (tid < PLEN) s_w[tid] = (tid < plen) ? __expf(s_scores[tid] - mx) : 0.f;
    __syncthreads();
    if (wv == 0) {
        float ss = 0.f;
        for (int p = lane; p < PLEN; p += 64) ss += s_w[p];
        ss = wave_sum(ss);
        if (lane == 0) s_bc[1] = 1.f / ss;
    }
    __syncthreads();
    const float inv_den = s_bc[1];
    const int d0 = tid << 1;
    float ca = 0.f, cb = 0.f;
    #pragma unroll 4
    for (int p = 0; p < PROWS; ++p) {
        const half2v pv2 = *(const half2v*)&s_post[(size_t)p*PDIM + d0];
        const float wp = s_w[p];
        ca += wp * (float)pv2[0];
        cb += wp * (float)pv2[1];
    }
    #pragma unroll 4
    for (int p = PROWS; p < PLEN; ++p) {
        const half2v pv2 = *(const half2v*)(post_h + ((size_t)p*BATCH + ab)*PDIM + d0);
        const float wp = s_w[p];
        ca += wp * (float)pv2[0];
        cb += wp * (float)pv2[1];
    }
    half2v cv; cv[0] = (_Float16)(ca * inv_den); cv[1] = (_Float16)(cb * inv_den);
    *(half2v*)&ctx_h[(size_t)ab*PDIM + d0] = cv;
}

// ======== gate kernel (per step): 64 blocks x 256 thr, 16 h-cols each ========
__global__ __launch_bounds__(256) void k_gate(
    const float* __restrict__ b_ih, const float* __restrict__ b_hh,
    const float* __restrict__ h_init, const int* __restrict__ length,
    float* __restrict__ out, int t, char* __restrict__ ws)
{
    const int tid  = threadIdx.x;
    const int lane = tid & 63;
    const int wv   = tid >> 6;
    const int j0   = blockIdx.x * 16;
    const _Float16* wih_h = (const _Float16*)(ws + OFF_WIH);
    const _Float16* whh_h = (const _Float16*)(ws + OFF_WHH);
    const _Float16* inc_h = (const _Float16*)(ws + OFF_INC);
    const _Float16* ctx_h = (const _Float16*)(ws + OFF_CTX);
    _Float16* hb          = (_Float16*)(ws + OFF_HB);
    const _Float16* hin   = hb + (size_t)(t & 1)*BATCH*HDIM;
    _Float16* hout        = hb + (size_t)((t + 1) & 1)*BATCH*HDIM;

    const int j = j0 + (lane & 15);
    const float bsr  = b_ih[j] + b_hh[j];
    const float bsz  = b_ih[HDIM + j] + b_hh[HDIM + j];
    const float bin_ = b_ih[2*HDIM + j];
    const float bhn  = b_hh[2*HDIM + j];

    f32x4 ghr = {0.f,0.f,0.f,0.f}, ghz = {0.f,0.f,0.f,0.f}, ghn_ = {0.f,0.f,0.f,0.f};
    f32x4 gir = {0.f,0.f,0.f,0.f}, giz = {0.f,0.f,0.f,0.f}, gin_ = {0.f,0.f,0.f,0.f};
    mfma_acc3(ghr, ghz, ghn_, hin + (size_t)(wv*16)*HDIM, HDIM,
              whh_h + (size_t)j0*HDIM,
              whh_h + (size_t)(HDIM + j0)*HDIM,
              whh_h + (size_t)(2*HDIM + j0)*HDIM, HDIM, HDIM/32, lane);
    mfma_acc3(gir, giz, gin_, inc_h + ((size_t)t*BATCH + wv*16)*EDIM, EDIM,
              wih_h + (size_t)j0*HDIM,
              wih_h + (size_t)(HDIM + j0)*HDIM,
              wih_h + (size_t)(2*HDIM + j0)*HDIM, HDIM, EDIM/32, lane);
    mfma_acc3(gir, giz, gin_, ctx_h + (size_t)(wv*16)*PDIM, PDIM,
              wih_h + (size_t)j0*HDIM + PDIM,
              wih_h + (size_t)(HDIM + j0)*HDIM + PDIM,
              wih_h + (size_t)(2*HDIM + j0)*HDIM + PDIM, HDIM, PDIM/32, lane);

    const int r0 = wv*16 + ((lane >> 4) << 2);
    #pragma unroll
    for (int r = 0; r < 4; ++r) {
        const int b = r0 + r;
        // fp32 previous-h: exact value R11 carried in registers (out stores fp32 h)
        const float hp = (t == 0) ? h_init[j] : out[(size_t)(t-1)*BATCH*HDIM + (size_t)b*HDIM + j];
        const int lenb = length[b];
        const float rg = 1.f / (1.f + __expf(-(gir[r] + ghr[r] + bsr)));
        const float zg = 1.f / (1.f + __expf(-(giz[r] + ghz[r] + bsz)));
        const float e2 = __expf(2.f * ((gin_[r] + bin_) + rg * (ghn_[r] + bhn)));
        const float ng = 1.f - 2.f / (e2 + 1.f);        // tanh
        float hv = (1.f - zg) * ng + zg * hp;
        if (lenb <= t) hv = 0.f;
        out[(size_t)t*BATCH*HDIM + (size_t)b*HDIM + j] = hv;
        hout[(size_t)b*HDIM + j] = (_Float16)hv;
        if (t == S_LEN - 1)
            out[(size_t)S_LEN*BATCH*HDIM + (size_t)b*HDIM + j] = hv;  // h_last
    }
}

extern "C" void kernel_launch(void* const* d_in, const int* in_sizes, int n_in,
                              void* d_out, int out_size, void* d_ws, size_t ws_size,
                              hipStream_t stream) {
    (void)in_sizes; (void)n_in; (void)out_size; (void)ws_size;
    const float* incoming    = (const float*)d_in[0];
    const float* post        = (const float*)d_in[1];
    const float* h_init      = (const float*)d_in[2];
    const float* w_ih        = (const float*)d_in[3];
    const float* w_hh        = (const float*)d_in[4];
    const float* b_ih        = (const float*)d_in[5];
    const float* b_hh        = (const float*)d_in[6];
    const float* wq          = (const float*)d_in[7];
    const float* bq          = (const float*)d_in[8];
    const int*   length      = (const int*)d_in[9];
    const int*   post_length = (const int*)d_in[10];
    float* out = (float*)d_out;
    char* ws = (char*)d_ws;

    k_stage<<<256, 256, 0, stream>>>(w_ih, w_hh, wq, incoming, post, h_init, ws);
    for (int t = 0; t < S_LEN; ++t) {
        k_query<<<128, 64, 0, stream>>>(bq, t, ws);
        k_attn<<<64, 256, 0, stream>>>(post_length, t, ws);
        k_gate<<<64, 256, 0, stream>>>(b_ih, b_hh, h_init, length, out, t, ws);
    }
}

// Round 13
// 5565.124 us; speedup vs baseline: 1.3116x; 1.3116x over previous
//
#include <hip/hip_runtime.h>

// ---------------- problem dims ----------------
#define S_LEN 128
#define BATCH 64
#define EDIM  512
#define PLEN  160
#define PDIM  512
#define HDIM  1024
#define G3    3072      // 3*H
#define NBLK  128       // 64 gate blocks + 64 attention blocks (1 per batch)
#define NTHR  256
#define PROWS 144       // post rows resident in LDS; rows 144..159 streamed from L2

typedef _Float16 half8v  __attribute__((ext_vector_type(8)));
typedef _Float16 half4v  __attribute__((ext_vector_type(4)));
typedef _Float16 half2v  __attribute__((ext_vector_type(2)));
typedef float    f32x4   __attribute__((ext_vector_type(4)));

// ---------------- workspace layout (bytes) ----------------
// ctrl: arrive flags 128 slots @ stride 32 uints
#define CTRL_UINTS 24576
#define OFF_CTRL ((size_t)0)                                  // 96 KiB
#define OFF_WIH  ((size_t)(CTRL_UINTS*4))                     // fp16 [3072][1024]
#define OFF_WHH  (OFF_WIH  + (size_t)G3*HDIM*2)               // fp16 [3072][1024]
#define OFF_INC  (OFF_WHH  + (size_t)G3*HDIM*2)               // fp16 [128][64][512]
#define OFF_POST (OFF_INC  + (size_t)S_LEN*BATCH*EDIM*2)      // fp16 [160][64][512]
#define OFF_HB   (OFF_POST + (size_t)PLEN*BATCH*PDIM*2)       // fp16 [2][64][1024]
#define OFF_CTX  (OFF_HB   + (size_t)2*BATCH*HDIM*2)          // fp16 [64][512]
#define OFF_QP   (OFF_CTX  + (size_t)BATCH*PDIM*2)            // f32  [64 kblk][64 b][512 c] = 8MB
// total ~38 MB

__global__ void init_ctrl(unsigned* u) {
    int i = threadIdx.x + blockIdx.x * blockDim.x;
    if (i < CTRL_UINTS) u[i] = 0u;
}

__device__ __forceinline__ float wave_sum(float v) {
    v += __shfl_xor(v, 32); v += __shfl_xor(v, 16); v += __shfl_xor(v, 8);
    v += __shfl_xor(v, 4);  v += __shfl_xor(v, 2);  v += __shfl_xor(v, 1);
    return v;
}
__device__ __forceinline__ float wave_max(float v) {
    v = fmaxf(v, __shfl_xor(v, 32)); v = fmaxf(v, __shfl_xor(v, 16));
    v = fmaxf(v, __shfl_xor(v, 8));  v = fmaxf(v, __shfl_xor(v, 4));
    v = fmaxf(v, __shfl_xor(v, 2));  v = fmaxf(v, __shfl_xor(v, 1));
    return v;
}

// One-hop grid barrier (R11: release store + relaxed hot-spin poll + acquire).
__device__ __forceinline__ void gbar(unsigned* arrive, unsigned& gen, int tid, int blk) {
    gen++;
    __syncthreads();   // drains vmcnt before s_barrier -> all block stores flushed w/ release
    if (tid == 0)
        __hip_atomic_store(&arrive[blk * 32], gen, __ATOMIC_RELEASE, __HIP_MEMORY_SCOPE_AGENT);
    if (tid < NBLK) {
        unsigned* fl = &arrive[tid * 32];
        while (__hip_atomic_load(fl, __ATOMIC_RELAXED, __HIP_MEMORY_SCOPE_AGENT) < gen) { }
        __hip_atomic_load(fl, __ATOMIC_ACQUIRE, __HIP_MEMORY_SCOPE_AGENT);
    }
    __syncthreads();
}

// three output tiles sharing one A stream (r,z,n gate rows)
__device__ __forceinline__ void mfma_acc3(f32x4& a0, f32x4& a1, f32x4& a2,
        const _Float16* __restrict__ A, int lda,
        const _Float16* __restrict__ B0, const _Float16* __restrict__ B1,
        const _Float16* __restrict__ B2, int ldb, int ksteps, int lane) {
    const _Float16* ap = A  + (size_t)(lane & 15) * lda + ((lane >> 4) << 3);
    const _Float16* p0 = B0 + (size_t)(lane & 15) * ldb + ((lane >> 4) << 3);
    const _Float16* p1 = B1 + (size_t)(lane & 15) * ldb + ((lane >> 4) << 3);
    const _Float16* p2 = B2 + (size_t)(lane & 15) * ldb + ((lane >> 4) << 3);
    #pragma unroll
    for (int ks = 0; ks < ksteps; ++ks) {
        half8v av = *(const half8v*)ap;
        a0 = __builtin_amdgcn_mfma_f32_16x16x32_f16(av, *(const half8v*)p0, a0, 0, 0, 0);
        a1 = __builtin_amdgcn_mfma_f32_16x16x32_f16(av, *(const half8v*)p1, a1, 0, 0, 0);
        a2 = __builtin_amdgcn_mfma_f32_16x16x32_f16(av, *(const half8v*)p2, a2, 0, 0, 0);
        ap += 32; p0 += 32; p1 += 32; p2 += 32;
    }
}

// rank-16 partial query: qpart[blk][b][c] = h_tile[b, j0..j0+15] . wq[c, j0..j0+15]
// via ONE zero-padded 16x16x32 MFMA per (m,n) tile; A (s_hq [64][32]) and
// B (s_wqp [512][32]) both LDS-resident, k=16..31 are zeros -> exact dot-16.
__device__ __forceinline__ void qpart_mfma(const _Float16* s_hq, const _Float16* s_wqp,
                                           float* __restrict__ qpart, int blk,
                                           int lane, int wv) {
    const int ko = (lane >> 4) << 3;
    const half8v af = *(const half8v*)(s_hq + (size_t)(wv*16 + (lane & 15))*32 + ko);
    const int b0 = wv*16 + ((lane >> 4) << 2);
    #pragma unroll 4
    for (int nt = 0; nt < 32; ++nt) {
        const half8v bf = *(const half8v*)(s_wqp + (size_t)(nt*16 + (lane & 15))*32 + ko);
        f32x4 acc = {0.f,0.f,0.f,0.f};
        acc = __builtin_amdgcn_mfma_f32_16x16x32_f16(af, bf, acc, 0, 0, 0);
        const int qc = nt*16 + (lane & 15);
        #pragma unroll
        for (int r = 0; r < 4; ++r)
            qpart[((size_t)blk*BATCH + b0 + r)*PDIM + qc] = acc[r];
    }
}

__global__ __launch_bounds__(NTHR, 1) void gru_main(
    const float* __restrict__ incoming, const float* __restrict__ post,
    const float* __restrict__ h_init,   const float* __restrict__ w_ih,
    const float* __restrict__ w_hh,     const float* __restrict__ b_ih,
    const float* __restrict__ b_hh,     const float* __restrict__ wq,
    const float* __restrict__ bq,       const int* __restrict__ length,
    const int* __restrict__ post_length, float* __restrict__ out,
    char* __restrict__ ws)
{
    const int tid  = threadIdx.x;
    const int blk  = blockIdx.x;
    const int lane = tid & 63;
    const int wv   = tid >> 6;

    unsigned* arrive = (unsigned*)(ws + OFF_CTRL);        // 128 x stride32
    _Float16* wih_h  = (_Float16*)(ws + OFF_WIH);
    _Float16* whh_h  = (_Float16*)(ws + OFF_WHH);
    _Float16* inc_h  = (_Float16*)(ws + OFF_INC);
    _Float16* post_h = (_Float16*)(ws + OFF_POST);
    _Float16* hb     = (_Float16*)(ws + OFF_HB);          // [2][64][1024]
    _Float16* ctx_h  = (_Float16*)(ws + OFF_CTX);
    float*    qpart  = (float*)(ws + OFF_QP);             // [64][64][512]

    // s_post doubles as gate-block scratch: s_wqp [512][32] @0 (32KB), s_hq [64][32] @32KB (4KB)
    __shared__ __align__(16) _Float16 s_post[PROWS * PDIM];   // 144 KB
    __shared__ __align__(16) _Float16 s_q[PDIM];              // 1 KB
    __shared__ float s_scores[PLEN];
    __shared__ float s_w[PLEN];
    __shared__ float s_bc[2];
    _Float16* s_wqp = s_post;
    _Float16* s_hq  = s_post + 512*32;

    unsigned gen = 0;

    // ---------------- per-block loop-invariant hoists ----------------
    float bsr = 0.f, bsz = 0.f, bin_ = 0.f, bhn = 0.f;
    float hp[4] = {0.f, 0.f, 0.f, 0.f};
    int lenb[4] = {0, 0, 0, 0};
    int j0 = 0, ab = 0, plen = 0;
    if (blk < 64) {                       // gate block: owns h-cols j0..j0+15
        j0 = blk * 16;
        const int j = j0 + (lane & 15);
        bsr  = b_ih[j] + b_hh[j];
        bsz  = b_ih[HDIM + j] + b_hh[HDIM + j];
        bin_ = b_ih[2*HDIM + j];
        bhn  = b_hh[2*HDIM + j];
        const float hi = h_init[j];
        const int r0 = wv*16 + ((lane >> 4) << 2);
        #pragma unroll
        for (int r = 0; r < 4; ++r) { hp[r] = hi; lenb[r] = length[r0 + r]; }
    } else {                              // attention block: owns batch ab
        ab = blk - 64;
        plen = post_length[ab];
    }

    // ---------------- init: fp32 -> fp16 conversions (grid-strided) ----------------
    {
        const int NV4_W    = G3*HDIM/4;
        const int NV4_INC  = S_LEN*BATCH*EDIM/4;
        const int NV4_POST = PLEN*BATCH*PDIM/4;
        const int TOT = 2*NV4_W + NV4_INC + NV4_POST;
        for (int i = blk*NTHR + tid; i < TOT; i += NBLK*NTHR) {
            const float* s; _Float16* dp; int o;
            if (i < NV4_W)                  { s = w_ih;     dp = wih_h;  o = i; }
            else if (i < 2*NV4_W)           { s = w_hh;     dp = whh_h;  o = i - NV4_W; }
            else if (i < 2*NV4_W + NV4_INC) { s = incoming; dp = inc_h;  o = i - 2*NV4_W; }
            else                            { s = post;     dp = post_h; o = i - 2*NV4_W - NV4_INC; }
            f32x4 v = *(const f32x4*)(s + (size_t)o*4);
            half4v hv4 = {(_Float16)v.x, (_Float16)v.y, (_Float16)v.z, (_Float16)v.w};
            *(half4v*)(dp + (size_t)o*4) = hv4;
        }
        for (int i = blk*NTHR + tid; i < BATCH*HDIM; i += NBLK*NTHR)
            hb[i] = (_Float16)h_init[i & (HDIM-1)];       // hb buffer 0 = h(0)
    }
    if (blk < 64) {
        // gate block: stage own wq slice [512 c][16 k] zero-padded to k=32 (from fp32 wq)
        for (int i = tid; i < 512*32; i += NTHR) {
            const int c = i >> 5, k = i & 31;
            s_wqp[i] = (k < 16) ? (_Float16)wq[(size_t)c*HDIM + j0 + k] : (_Float16)0.f;
        }
        // s_hq(0) = fp16(h_init) broadcast over batches, zero-padded
        for (int i = tid; i < 64*32; i += NTHR) {
            const int k = i & 31;
            s_hq[i] = (k < 16) ? (_Float16)h_init[j0 + k] : (_Float16)0.f;
        }
        __syncthreads();
        qpart_mfma(s_hq, s_wqp, qpart, blk, lane, wv);    // qpart for t=0
    } else {
        // attention block: stage post rows 0..PROWS-1 of own batch into LDS
        for (int i = tid; i < PROWS*PDIM; i += NTHR) {
            const int p = i >> 9, d = i & (PDIM-1);
            s_post[i] = (_Float16)post[((size_t)p*BATCH + ab)*PDIM + d];
        }
    }
    gbar(arrive, gen, tid, blk);   // weights/inc/post/h/qpart(0) ready

    // ---------------- time loop: 2 grid barriers per step (no qflag) ----------------
    for (int t = 0; t < S_LEN; ++t) {
        f32x4 ghr = {0.f,0.f,0.f,0.f}, ghz = {0.f,0.f,0.f,0.f}, ghn_ = {0.f,0.f,0.f,0.f};
        f32x4 gir = {0.f,0.f,0.f,0.f}, giz = {0.f,0.f,0.f,0.f}, gin_ = {0.f,0.f,0.f,0.f};

        if (blk < 64) {
            // ==== P1 gate: gh = h@Whh^T (r,z,n); gi_x = x_t@Wih[:, :512]^T ====
            mfma_acc3(ghr, ghz, ghn_, hb + (size_t)(t & 1)*BATCH*HDIM + (size_t)(wv*16)*HDIM, HDIM,
                      whh_h + (size_t)j0*HDIM,
                      whh_h + (size_t)(HDIM + j0)*HDIM,
                      whh_h + (size_t)(2*HDIM + j0)*HDIM, HDIM, HDIM/32, lane);
            mfma_acc3(gir, giz, gin_, inc_h + ((size_t)t*BATCH + wv*16)*EDIM, EDIM,
                      wih_h + (size_t)j0*HDIM,
                      wih_h + (size_t)(HDIM + j0)*HDIM,
                      wih_h + (size_t)(2*HDIM + j0)*HDIM, HDIM, EDIM/32, lane);
        } else {
            // ==== P1 attention: query = Σ qpart + bq, scores, softmax, ctx ====
            half8v srow[4];
            #pragma unroll
            for (int i = 0; i < 4; ++i)
                srow[i] = *(const half8v*)(post_h +
                            ((size_t)(PROWS + wv + 4*i)*BATCH + ab)*PDIM + lane*8);
            // sum the 64 rank-16 partials for own batch (L3-resident, coalesced)
            {
                const int c0 = tid << 1;
                float qx = 0.f, qy = 0.f;
                #pragma unroll 8
                for (int k = 0; k < 64; ++k) {
                    const float2 v = *(const float2*)&qpart[((size_t)k*BATCH + ab)*PDIM + c0];
                    qx += v.x; qy += v.y;
                }
                s_q[c0]     = (_Float16)(qx + bq[c0]);
                s_q[c0 + 1] = (_Float16)(qy + bq[c0 + 1]);
            }
            __syncthreads();
            const half8v qv = *(const half8v*)&s_q[lane*8];
            #pragma unroll 2
            for (int p = wv; p < PROWS; p += 4) {
                const half8v pv = *(const half8v*)&s_post[(size_t)p*PDIM + lane*8];
                float sd = 0.f;
                #pragma unroll
                for (int jj = 0; jj < 8; ++jj) sd += (float)pv[jj] * (float)qv[jj];
                sd = wave_sum(sd);
                if (lane == 0) s_scores[p] = sd;
            }
            #pragma unroll
            for (int i = 0; i < 4; ++i) {
                const half8v pv = srow[i];
                float sd = 0.f;
                #pragma unroll
                for (int jj = 0; jj < 8; ++jj) sd += (float)pv[jj] * (float)qv[jj];
                sd = wave_sum(sd);
                if (lane == 0) s_scores[PROWS + wv + 4*i] = sd;
            }
            __syncthreads();
            if (wv == 0) {
                float m = -1e30f;
                for (int p = lane; p < plen; p += 64) m = fmaxf(m, s_scores[p]);
                m = wave_max(m);
                if (lane == 0) s_bc[0] = m;
            }
            __syncthreads();
            const float mx = s_bc[0];
            if (tid < PLEN) s_w[tid] = (tid < plen) ? __expf(s_scores[tid] - mx) : 0.f;
            __syncthreads();
            if (wv == 0) {
                float ss = 0.f;
                for (int p = lane; p < PLEN; p += 64) ss += s_w[p];
                ss = wave_sum(ss);
                if (lane == 0) s_bc[1] = 1.f / ss;
            }
            __syncthreads();
            const float inv_den = s_bc[1];
            const int d0 = tid << 1;
            float ca = 0.f, cb = 0.f;
            #pragma unroll 4
            for (int p = 0; p < PROWS; ++p) {
                const half2v pv2 = *(const half2v*)&s_post[(size_t)p*PDIM + d0];
                const float wp = s_w[p];
                ca += wp * (float)pv2[0];
                cb += wp * (float)pv2[1];
            }
            #pragma unroll 4
            for (int p = PROWS; p < PLEN; ++p) {
                const half2v pv2 = *(const half2v*)(post_h + ((size_t)p*BATCH + ab)*PDIM + d0);
                const float wp = s_w[p];
                ca += wp * (float)pv2[0];
                cb += wp * (float)pv2[1];
            }
            half2v cv; cv[0] = (_Float16)(ca * inv_den); cv[1] = (_Float16)(cb * inv_den);
            *(half2v*)&ctx_h[(size_t)ab*PDIM + d0] = cv;
        }
        gbar(arrive, gen, tid, blk);   // barrier W: ctx ready

        if (blk < 64) {
            // ==== P2 gate: gi += ctx@Wih[:, 512:]^T, gate math, h update, qpart ====
            mfma_acc3(gir, giz, gin_, ctx_h + (size_t)(wv*16)*PDIM, PDIM,
                      wih_h + (size_t)j0*HDIM + PDIM,
                      wih_h + (size_t)(HDIM + j0)*HDIM + PDIM,
                      wih_h + (size_t)(2*HDIM + j0)*HDIM + PDIM, HDIM, PDIM/32, lane);
            _Float16* hout = hb + (size_t)((t + 1) & 1)*BATCH*HDIM;
            const int j  = j0 + (lane & 15);
            const int r0 = wv*16 + ((lane >> 4) << 2);
            float hvv[4];
            #pragma unroll
            for (int r = 0; r < 4; ++r) {
                const int b = r0 + r;
                const float rg = 1.f / (1.f + __expf(-(gir[r] + ghr[r] + bsr)));
                const float zg = 1.f / (1.f + __expf(-(giz[r] + ghz[r] + bsz)));
                const float e2 = __expf(2.f * ((gin_[r] + bin_) + rg * (ghn_[r] + bhn)));
                const float ng = 1.f - 2.f / (e2 + 1.f);        // tanh
                float hv = (1.f - zg) * ng + zg * hp[r];
                if (lenb[r] <= t) hv = 0.f;
                hp[r] = hv; hvv[r] = hv;
                out[(size_t)t*BATCH*HDIM + (size_t)b*HDIM + j] = hv;
                hout[(size_t)b*HDIM + j] = (_Float16)hv;
                if (t == S_LEN - 1)
                    out[(size_t)S_LEN*BATCH*HDIM + (size_t)b*HDIM + j] = hv;  // h_last
            }
            // rank-16 partial query for NEXT step (k=16..31 pad stays zero)
            __syncthreads();   // s_hq WAR vs this step's qpart_mfma reads... (prev reads done pre-barW)
            #pragma unroll
            for (int r = 0; r < 4; ++r)
                s_hq[(size_t)(r0 + r)*32 + (lane & 15)] = (_Float16)hvv[r];
            __syncthreads();
            qpart_mfma(s_hq, s_wqp, qpart, blk, lane, wv);
        }
        if (t < S_LEN - 1) gbar(arrive, gen, tid, blk);   // barrier H: h + qpart ready
    }
}

extern "C" void kernel_launch(void* const* d_in, const int* in_sizes, int n_in,
                              void* d_out, int out_size, void* d_ws, size_t ws_size,
                              hipStream_t stream) {
    (void)in_sizes; (void)n_in; (void)out_size; (void)ws_size;
    const float* incoming    = (const float*)d_in[0];
    const float* post        = (const float*)d_in[1];
    const float* h_init      = (const float*)d_in[2];
    const float* w_ih        = (const float*)d_in[3];
    const float* w_hh        = (const float*)d_in[4];
    const float* b_ih        = (const float*)d_in[5];
    const float* b_hh        = (const float*)d_in[6];
    const float* wq          = (const float*)d_in[7];
    const float* bq          = (const float*)d_in[8];
    const int*   length      = (const int*)d_in[9];
    const int*   post_length = (const int*)d_in[10];
    float* out = (float*)d_out;

    init_ctrl<<<96, 256, 0, stream>>>((unsigned*)d_ws);
    gru_main<<<NBLK, NTHR, 0, stream>>>(incoming, post, h_init, w_ih, w_hh, b_ih, b_hh,
                                        wq, bq, length, post_length, out, (char*)d_ws);
}